// Round 8
// baseline (3831.073 us; speedup 1.0000x reference)
//
#include <hip/hip_runtime.h>
#include <hip/hip_bf16.h>

#define D 768
#define BB 32
#define XX 256
#define CH 3816   // vocab chunk per k_fin block (8 chunks cover 30522)
#define NLG 128   // attn logit blocks (scheduled first in k_mid)
#define MIDREP 5  // measurement: vocab stream+MFMA repeated (idempotent)

typedef __bf16 bf16x8 __attribute__((ext_vector_type(8)));
typedef float  f32x4  __attribute__((ext_vector_type(4)));

// ---------------------------------------------------------------------------
// K0: one-time: emb fp32 -> bf16
// ---------------------------------------------------------------------------
__global__ __launch_bounds__(256) void k_cvt(const float* __restrict__ src,
                                             __bf16* __restrict__ dst, int n8)
{
    int i = blockIdx.x * 256 + threadIdx.x;
    if (i < n8) {
        float4 f0 = *(const float4*)(src + (size_t)i * 8);
        float4 f1 = *(const float4*)(src + (size_t)i * 8 + 4);
        bf16x8 o;
        o[0] = (__bf16)f0.x; o[1] = (__bf16)f0.y; o[2] = (__bf16)f0.z; o[3] = (__bf16)f0.w;
        o[4] = (__bf16)f1.x; o[5] = (__bf16)f1.y; o[6] = (__bf16)f1.z; o[7] = (__bf16)f1.w;
        *(bf16x8*)(dst + (size_t)i * 8) = o;
    }
}

// ---------------------------------------------------------------------------
// K0b: one-time: penc[b][x] = wgen[1536:2304] . enc[b,x,:]
// ---------------------------------------------------------------------------
__global__ __launch_bounds__(256) void k_penc(
    const float* __restrict__ enc, const float* __restrict__ wgen,
    float* __restrict__ penc)
{
    const int t = threadIdx.x;
    const int b = blockIdx.x >> 2, c = blockIdx.x & 3;
    const int x0 = c * 64;
    const int l = t & 31;
    float4 wr[6];
    #pragma unroll
    for (int p = 0; p < 6; ++p)
        wr[p] = *(const float4*)(wgen + 1536 + l * 4 + p * 128);
    for (int g = 0; g < 8; ++g) {
        int x = x0 + g * 8 + (t >> 5);
        const float* er = enc + ((size_t)b * XX + x) * D + l * 4;
        float acc = 0.f;
        #pragma unroll
        for (int p = 0; p < 6; ++p) {
            float4 e = *(const float4*)(er + p * 128);
            acc += e.x * wr[p].x + e.y * wr[p].y + e.z * wr[p].z + e.w * wr[p].w;
        }
        #pragma unroll
        for (int m = 1; m <= 16; m <<= 1) acc += __shfl_xor(acc, m);
        if (l == 0) penc[b * XX + x] = acc;
    }
}

// ---------------------------------------------------------------------------
// K1: GRU gates GEMM, fp32. gT[row 0..4607][b 0..31]. grid 576 x 256.
// (Verbatim round-4 best.)
// ---------------------------------------------------------------------------
__global__ __launch_bounds__(256) void k_gates(
    const float* __restrict__ xbase, long xbstride,
    const unsigned long long* __restrict__ toks,
    const float* __restrict__ hin,
    const float* __restrict__ wih, const float* __restrict__ whh,
    float* __restrict__ gT)
{
    __shared__ __align__(16) float vec[BB][132];
    __shared__ int tokl[BB];
    const int t = threadIdx.x, bid = blockIdx.x;
    const int b = t & 31, rl = t >> 5;
    const int rglob = bid * 8 + rl;
    const bool isH = rglob >= 2304;
    const int row = isH ? rglob - 2304 : rglob;
    const float* w = (isH ? whh : wih) + (size_t)row * D;
    if (t < 32) tokl[t] = toks ? (int)(0xFFFFFFFFu - (unsigned)(toks[t] & 0xFFFFFFFFull)) : 0;

    float acc = 0.f;
    for (int c = 0; c < 6; ++c) {
        const int kc = c * 128;
        __syncthreads();
        for (int p = 0; p < 4; ++p) {
            int fid = t + 256 * p;
            int bb = fid >> 5, k4 = (fid & 31) * 4;
            const float* src;
            if (isH) src = hin + (size_t)bb * D;
            else     src = toks ? (xbase + (size_t)tokl[bb] * D)
                                : (xbase + (size_t)bb * xbstride);
            *(float4*)&vec[bb][k4] = *(const float4*)(src + kc + k4);
        }
        __syncthreads();
        #pragma unroll
        for (int k4 = 0; k4 < 128; k4 += 4) {
            float4 wv = *(const float4*)(w + kc + k4);
            float4 xv = *(const float4*)&vec[b][k4];
            acc += wv.x * xv.x + wv.y * xv.y + wv.z * xv.z + wv.w * xv.w;
        }
    }
    gT[(size_t)rglob * 32 + b] = acc;
}

// ---------------------------------------------------------------------------
// K2: GRU combine -> h (fp32 + bf16); zero argz; pgen partials. grid 96 x 256.
// (Verbatim round-4.)
// ---------------------------------------------------------------------------
__global__ __launch_bounds__(256) void k_comb(
    const float* __restrict__ gT,
    const float* __restrict__ bih, const float* __restrict__ bhh,
    const float* __restrict__ hin,
    const float* __restrict__ xbase, long xbstride,
    const unsigned long long* __restrict__ toks,
    const float* __restrict__ wgen,
    float* __restrict__ hout, __bf16* __restrict__ hbf,
    float* __restrict__ pgen_part,
    unsigned long long* __restrict__ argz)
{
    __shared__ float part[8][32];
    const int t = threadIdx.x, bid = blockIdx.x;
    const int b = t & 31, dl = t >> 5;
    const int d = bid * 8 + dl;
    if (bid == 0 && t < 32) argz[t] = 0ULL;
    float ir = gT[(size_t)d * 32 + b]            + bih[d];
    float iz = gT[(size_t)(768 + d) * 32 + b]    + bih[768 + d];
    float in_ = gT[(size_t)(1536 + d) * 32 + b]  + bih[1536 + d];
    float hr = gT[(size_t)(2304 + d) * 32 + b]   + bhh[d];
    float hz = gT[(size_t)(3072 + d) * 32 + b]   + bhh[768 + d];
    float hn = gT[(size_t)(3840 + d) * 32 + b]   + bhh[1536 + d];
    float r = 1.0f / (1.0f + expf(-(ir + hr)));
    float z = 1.0f / (1.0f + expf(-(iz + hz)));
    float n = tanhf(in_ + r * hn);
    float hold = hin[(size_t)b * D + d];
    float hv = (1.0f - z) * n + z * hold;
    hout[(size_t)b * D + d] = hv;
    hbf[(size_t)b * D + d] = (__bf16)hv;
    float xv;
    if (toks) {
        int tok = (int)(0xFFFFFFFFu - (unsigned)(toks[b] & 0xFFFFFFFFull));
        xv = xbase[(size_t)tok * D + d];
    } else {
        xv = xbase[(size_t)b * xbstride + d];
    }
    part[dl][b] = wgen[d] * hv + wgen[768 + d] * xv;
    __syncthreads();
    if (t < 32) {
        float s = 0.f;
        #pragma unroll
        for (int i = 0; i < 8; ++i) s += part[i][t];
        pgen_part[(size_t)t * 96 + bid] = s;
    }
}

// ---------------------------------------------------------------------------
// K3: attn logit blocks FIRST (bid < NLG), then vocab MFMA blocks.
// MEASUREMENT ROUND: the vocab stream+MFMA body runs MIDREP times (idempotent;
// LDS re-staged each rep, accumulators reset each rep, asm keep-alive defeats
// DCE of reps 0..MIDREP-2). Final rep's values are bit-identical to the
// single-pass kernel. dur delta / (32*(MIDREP-1)) = tau_mid_vocab.
// ---------------------------------------------------------------------------
struct __align__(16) MSE { float sh[64][33]; float dsum[32]; };
union  __align__(16) MSU { __bf16 buf[2][64][128]; MSE e; };

__device__ __forceinline__ void stage_chunk(
    const char* __restrict__ embb, int vb, int c, int w, int lane,
    char* lbuf, int V)
{
    #pragma unroll
    for (int i = 0; i < 4; ++i) {
        const int g = w * 4 + i;
        const int row = g * 4 + (lane >> 4);
        int grow = vb * 64 + row;
        grow = (grow < V) ? grow : (V - 1);
        const int cb = ((lane & 15) << 4) ^ ((row & 7) << 4);  // inverse swizzle on src
        const char* gp = embb + (size_t)grow * 1536 + (size_t)c * 256 + cb;
        char* lp = lbuf + g * 1024;                            // wave-uniform, linear dest
        __builtin_amdgcn_global_load_lds(
            (const __attribute__((address_space(1))) unsigned int*)gp,
            (__attribute__((address_space(3))) unsigned int*)lp, 16, 0, 0);
    }
}

__global__ __launch_bounds__(256) void k_mid(
    const float* __restrict__ hnew, const __bf16* __restrict__ hbf,
    const __bf16* __restrict__ embbf,
    const float* __restrict__ enc, const int* __restrict__ ids,
    float* __restrict__ out, long outoff, long JKV,
    float* __restrict__ dpartT, float* __restrict__ logitw,
    int V, int NVB)
{
    __shared__ MSU u;
    const int t = threadIdx.x;
    const int bid = blockIdx.x;

    if (bid < NLG) {
        // -------------------- attn logit block (single pass) --------------------
        const int b = bid >> 2, c = bid & 3;
        const int x0 = c * 64;
        const int l = t & 31;
        float4 hr[6];
        #pragma unroll
        for (int p = 0; p < 6; ++p)
            hr[p] = *(const float4*)(hnew + (size_t)b * D + l * 4 + p * 128);
        #pragma unroll 4
        for (int g = 0; g < 8; ++g) {
            int x = x0 + g * 8 + (t >> 5);
            const float* er = enc + ((size_t)b * XX + x) * D + l * 4;
            float acc = 0.f;
            #pragma unroll
            for (int p = 0; p < 6; ++p) {
                float4 e = *(const float4*)(er + p * 128);
                acc += e.x * hr[p].x + e.y * hr[p].y + e.z * hr[p].z + e.w * hr[p].w;
            }
            #pragma unroll
            for (int m = 1; m <= 16; m <<= 1) acc += __shfl_xor(acc, m);
            if (l == 0) {
                int id = ids[b * XX + x];
                logitw[b * XX + x] = (id == 0) ? -1e9f : acc;
            }
        }
    } else {
        // -------------------- vocab MFMA block (LDS-staged, x MIDREP) --------------------
        const int vb = bid - NLG;          // 0..NVB-1
        const int lane = t & 63, w = t >> 6;
        const int col = lane & 15;
        const int hi = lane >> 4;          // 0..3
        const int vrow = vb * 64 + w * 16 + col;
        const bool ok = vrow < V;
        const __bf16* ap0 = hbf + (size_t)col * D + hi * 8;
        const __bf16* ap1 = hbf + (size_t)(col + 16) * D + hi * 8;
        const char* embb = (const char*)embbf;

        const int rl = w * 16 + col;
        const int swz = (rl & 7) << 4;
        f32x4 c0, c1;

        for (int rep = 0; rep < MIDREP; ++rep) {
            // prologue: stage chunk 0
            stage_chunk(embb, vb, 0, w, lane, (char*)&u.buf[0][0][0], V);
            c0 = f32x4{0.f, 0.f, 0.f, 0.f};
            c1 = f32x4{0.f, 0.f, 0.f, 0.f};
            for (int c = 0; c < 6; ++c) {
                if (c < 5) {
                    stage_chunk(embb, vb, c + 1, w, lane,
                                (char*)&u.buf[(c + 1) & 1][0][0], V);
                    asm volatile("s_waitcnt vmcnt(4)" ::: "memory");  // chunk c resident
                } else {
                    asm volatile("s_waitcnt vmcnt(0)" ::: "memory");
                }
                const char* bbuf = (const char*)&u.buf[c & 1][0][0];
                #pragma unroll
                for (int q = 0; q < 4; ++q) {
                    const int cbl = q * 64 + (hi << 4);
                    bf16x8 bv = *(const bf16x8*)(bbuf + rl * 256 + (cbl ^ swz));
                    const int kg = c * 128 + q * 32;
                    bf16x8 a0 = *(const bf16x8*)(ap0 + kg);
                    bf16x8 a1 = *(const bf16x8*)(ap1 + kg);
                    c0 = __builtin_amdgcn_mfma_f32_16x16x32_bf16(a0, bv, c0, 0, 0, 0);
                    c1 = __builtin_amdgcn_mfma_f32_16x16x32_bf16(a1, bv, c1, 0, 0, 0);
                }
            }
            // keep rep's results live so reps 0..MIDREP-2 are not DCE'd (rule #17)
            asm volatile("" :: "v"(c0[0]), "v"(c0[1]), "v"(c0[2]), "v"(c0[3]),
                              "v"(c1[0]), "v"(c1[1]), "v"(c1[2]), "v"(c1[3]));
        }

        // -------------------- epilogue (union reuse: sync first) --------------------
        __syncthreads();
        if (t < 32) u.e.dsum[t] = 0.f;
        __syncthreads();
        const int vloc = w * 16 + col;
        #pragma unroll
        for (int r = 0; r < 4; ++r) {
            int b0 = hi * 4 + r;
            float e0 = ok ? __expf(c0[r]) : 0.f;
            float e1 = ok ? __expf(c1[r]) : 0.f;
            u.e.sh[vloc][b0]      = e0;
            u.e.sh[vloc][b0 + 16] = e1;
            #pragma unroll
            for (int m = 1; m <= 8; m <<= 1) {
                e0 += __shfl_xor(e0, m);
                e1 += __shfl_xor(e1, m);
            }
            if (col == 0) {
                atomicAdd(&u.e.dsum[b0], e0);
                atomicAdd(&u.e.dsum[b0 + 16], e1);
            }
        }
        __syncthreads();
        if (t < 32) dpartT[(size_t)t * 512 + vb] = u.e.dsum[t];

        // coalesced store: each wave writes 8 b-rows, 64 consecutive floats
        const int vg = vb * 64 + lane;
        if (vg < V) {
            #pragma unroll
            for (int i = 0; i < 8; ++i) {
                int bb2 = w * 8 + i;
                out[(size_t)bb2 * JKV + outoff + vg] = u.e.sh[lane][bb2];
            }
        }
    }
}

// ---------------------------------------------------------------------------
// K4: finalize (verbatim round-4 best: grid 256, CH=3816).
// ---------------------------------------------------------------------------
__global__ __launch_bounds__(256) void k_fin(
    float* __restrict__ out, long outoff, long JKV,
    const float* __restrict__ dpartT, int npart,
    const float* __restrict__ logitw, const float* __restrict__ penc,
    const float* __restrict__ pgen_part, const float* __restrict__ bgen,
    const int* __restrict__ ids,
    unsigned long long* __restrict__ argz, int V)
{
    __shared__ float pctx[CH];
    __shared__ float red[256];
    __shared__ float aw[256];
    __shared__ unsigned long long wmax[4];
    const int t = threadIdx.x;
    const int b = blockIdx.x >> 3;
    const int c = blockIdx.x & 7;
    const int v0 = c * CH;

    // 1. denominator
    float s = 0.f;
    for (int i = t; i < npart; i += 256) s += dpartT[(size_t)b * 512 + i];
    red[t] = s;
    __syncthreads();
    for (int st = 128; st > 0; st >>= 1) {
        if (t < st) red[t] += red[t + st];
        __syncthreads();
    }
    const float rd = 1.0f / red[0];
    __syncthreads();

    // 2. attention softmax
    float l = logitw[b * XX + t];
    red[t] = l;
    __syncthreads();
    for (int st = 128; st > 0; st >>= 1) {
        if (t < st) red[t] = fmaxf(red[t], red[t + st]);
        __syncthreads();
    }
    float mx = red[0];
    __syncthreads();
    float e = expf(l - mx);
    red[t] = e;
    __syncthreads();
    for (int st = 128; st > 0; st >>= 1) {
        if (t < st) red[t] += red[t + st];
        __syncthreads();
    }
    float awv = e / red[0];
    aw[t] = awv;
    __syncthreads();

    // 3. p_gen
    float pv = awv * penc[b * XX + t] + ((t < 96) ? pgen_part[(size_t)b * 96 + t] : 0.f);
    red[t] = pv;
    __syncthreads();
    for (int st = 128; st > 0; st >>= 1) {
        if (t < st) red[t] += red[t + st];
        __syncthreads();
    }
    const float pg = 1.0f / (1.0f + expf(-(red[0] + bgen[0])));
    const float og = 1.0f - pg;

    // 4. scatter p_ctx chunk
    for (int i = t; i < CH; i += 256) pctx[i] = 0.f;
    __syncthreads();
    {
        int id = ids[b * XX + t];
        int rel = id - v0;
        if ((unsigned)rel < (unsigned)CH) atomicAdd(&pctx[rel], aw[t]);
    }
    __syncthreads();

    // 5. normalize + argmax
    unsigned long long pk = 0ULL;
    const int vend = (v0 + CH < V) ? CH : (V - v0);
    #pragma unroll
    for (int i = 0; i < 15; ++i) {
        int v = t + 256 * i;
        if (v < vend) {
            int vg = v0 + v;
            size_t o = (size_t)b * JKV + outoff + vg;
            float ev = out[o];
            float ps = pg * ev * rd + og * pctx[v];
            out[o] = ps;
            unsigned long long k2 = ((unsigned long long)__float_as_uint(ps) << 32)
                                  | (unsigned long long)(0xFFFFFFFFu - (unsigned)vg);
            if (k2 > pk) pk = k2;
        }
    }
    #pragma unroll
    for (int m = 1; m < 64; m <<= 1) {
        unsigned long long o2 = __shfl_xor(pk, m);
        if (o2 > pk) pk = o2;
    }
    if ((t & 63) == 0) wmax[t >> 6] = pk;
    __syncthreads();
    if (t == 0) {
        unsigned long long m0 = wmax[0];
        #pragma unroll
        for (int i2 = 1; i2 < 4; ++i2) if (wmax[i2] > m0) m0 = wmax[i2];
        atomicMax(&argz[b], m0);
    }
}

// ---------------------------------------------------------------------------
extern "C" void kernel_launch(void* const* d_in, const int* in_sizes, int n_in,
                              void* d_out, int out_size, void* d_ws, size_t ws_size,
                              hipStream_t stream)
{
    const float* dec  = (const float*)d_in[0];
    const float* hid  = (const float*)d_in[1];
    const float* enc  = (const float*)d_in[2];
    const int*   ids  = (const int*)d_in[3];
    const float* emb  = (const float*)d_in[5];
    const float* wih  = (const float*)d_in[6];
    const float* whh  = (const float*)d_in[7];
    const float* bih  = (const float*)d_in[8];
    const float* bhh  = (const float*)d_in[9];
    const float* wgen = (const float*)d_in[10];
    const float* bgen = (const float*)d_in[11];
    float* out = (float*)d_out;

    const int B = 32;
    const int J = in_sizes[0] / (B * D);           // 4
    const int V = in_sizes[5] / D;                 // 30522
    const int K = out_size / (B * J * V);          // 8
    const long JKV = (long)J * K * V;
    const int NVB = (V + 63) / 64;                 // 477

    // workspace carve
    char* w = (char*)d_ws;
    unsigned long long* argpack = (unsigned long long*)w; w += 1024; // 2 x 32
    float* gT        = (float*)w;  w += (size_t)4608 * 32 * 4;
    float* dpartT    = (float*)w;  w += (size_t)32 * 512 * 4;
    float* logitw    = (float*)w;  w += (size_t)B * XX * 4;
    float* penc      = (float*)w;  w += (size_t)B * XX * 4;
    float* pgen_part = (float*)w;  w += (size_t)B * 96 * 4;
    float* h0        = (float*)w;  w += (size_t)B * D * 4;
    float* h1        = (float*)w;  w += (size_t)B * D * 4;
    __bf16* hbf      = (__bf16*)w; w += (size_t)B * D * 2;
    __bf16* embbf    = (__bf16*)w; w += (size_t)V * D * 2;

    const int n8 = V * D / 8;
    k_cvt<<<dim3((n8 + 255) / 256), dim3(256), 0, stream>>>(emb, embbf, n8);
    k_penc<<<dim3(128), dim3(256), 0, stream>>>(enc, wgen, penc);

    int step = 0;
    for (int j = 0; j < J; ++j) {
        for (int kk = 0; kk < K; ++kk) {
            const int cur = step & 1;
            float* hout = (cur == 0) ? h0 : h1;
            const float* hin = (step == 0) ? hid : ((((step - 1) & 1) == 0) ? h0 : h1);
            const float* xbase;
            long xbs;
            const unsigned long long* toks;
            if (kk == 0) {
                xbase = dec + (size_t)j * D;
                xbs = (long)J * D;
                toks = nullptr;
            } else {
                xbase = emb;
                xbs = D;
                toks = argpack + ((step - 1) & 1) * 32;
            }
            unsigned long long* argz = argpack + cur * 32;
            const long outoff = (long)(j * K + kk) * V;

            k_gates<<<dim3(576), dim3(256), 0, stream>>>(
                xbase, xbs, toks, hin, wih, whh, gT);
            k_comb<<<dim3(96), dim3(256), 0, stream>>>(
                gT, bih, bhh, hin, xbase, xbs, toks, wgen, hout, hbf,
                pgen_part, argz);
            k_mid<<<dim3(NVB + NLG), dim3(256), 0, stream>>>(
                hout, hbf, embbf, enc, ids, out, outoff, JKV,
                dpartT, logitw, V, NVB);
            k_fin<<<dim3(256), dim3(256), 0, stream>>>(
                out, outoff, JKV, dpartT, NVB, logitw, penc, pgen_part,
                bgen, ids, argz, V);
            ++step;
        }
    }
}

// Round 9
// 2551.076 us; speedup vs baseline: 1.5017x; 1.5017x over previous
//
#include <hip/hip_runtime.h>
#include <hip/hip_bf16.h>

#define D 768
#define BB 32
#define XX 256
#define CHS 512   // vocab chunk per k_finp block (60 chunks x 32 b)
#define NCH 60
#define NLG 128   // attn logit blocks (scheduled first in k_mid)

typedef __bf16 bf16x8 __attribute__((ext_vector_type(8)));
typedef float  f32x4  __attribute__((ext_vector_type(4)));

// ---------------------------------------------------------------------------
// K0: one-time: emb fp32 -> bf16
// ---------------------------------------------------------------------------
__global__ __launch_bounds__(256) void k_cvt(const float* __restrict__ src,
                                             __bf16* __restrict__ dst, int n8)
{
    int i = blockIdx.x * 256 + threadIdx.x;
    if (i < n8) {
        float4 f0 = *(const float4*)(src + (size_t)i * 8);
        float4 f1 = *(const float4*)(src + (size_t)i * 8 + 4);
        bf16x8 o;
        o[0] = (__bf16)f0.x; o[1] = (__bf16)f0.y; o[2] = (__bf16)f0.z; o[3] = (__bf16)f0.w;
        o[4] = (__bf16)f1.x; o[5] = (__bf16)f1.y; o[6] = (__bf16)f1.z; o[7] = (__bf16)f1.w;
        *(bf16x8*)(dst + (size_t)i * 8) = o;
    }
}

// ---------------------------------------------------------------------------
// K0b: one-time: penc[b][x] = wgen[1536:2304] . enc[b,x,:]
// ---------------------------------------------------------------------------
__global__ __launch_bounds__(256) void k_penc(
    const float* __restrict__ enc, const float* __restrict__ wgen,
    float* __restrict__ penc)
{
    const int t = threadIdx.x;
    const int b = blockIdx.x >> 2, c = blockIdx.x & 3;
    const int x0 = c * 64;
    const int l = t & 31;
    float4 wr[6];
    #pragma unroll
    for (int p = 0; p < 6; ++p)
        wr[p] = *(const float4*)(wgen + 1536 + l * 4 + p * 128);
    for (int g = 0; g < 8; ++g) {
        int x = x0 + g * 8 + (t >> 5);
        const float* er = enc + ((size_t)b * XX + x) * D + l * 4;
        float acc = 0.f;
        #pragma unroll
        for (int p = 0; p < 6; ++p) {
            float4 e = *(const float4*)(er + p * 128);
            acc += e.x * wr[p].x + e.y * wr[p].y + e.z * wr[p].z + e.w * wr[p].w;
        }
        #pragma unroll
        for (int m = 1; m <= 16; m <<= 1) acc += __shfl_xor(acc, m);
        if (l == 0) penc[b * XX + x] = acc;
    }
}

// ---------------------------------------------------------------------------
// K1: GRU gates GEMM, fp32. gT[row 0..4607][b 0..31]. grid 576 x 256.
// (Verbatim round-4 best.)
// ---------------------------------------------------------------------------
__global__ __launch_bounds__(256) void k_gates(
    const float* __restrict__ xbase, long xbstride,
    const unsigned long long* __restrict__ toks,
    const float* __restrict__ hin,
    const float* __restrict__ wih, const float* __restrict__ whh,
    float* __restrict__ gT)
{
    __shared__ __align__(16) float vec[BB][132];
    __shared__ int tokl[BB];
    const int t = threadIdx.x, bid = blockIdx.x;
    const int b = t & 31, rl = t >> 5;
    const int rglob = bid * 8 + rl;
    const bool isH = rglob >= 2304;
    const int row = isH ? rglob - 2304 : rglob;
    const float* w = (isH ? whh : wih) + (size_t)row * D;
    if (t < 32) tokl[t] = toks ? (int)(0xFFFFFFFFu - (unsigned)(toks[t] & 0xFFFFFFFFull)) : 0;

    float acc = 0.f;
    for (int c = 0; c < 6; ++c) {
        const int kc = c * 128;
        __syncthreads();
        for (int p = 0; p < 4; ++p) {
            int fid = t + 256 * p;
            int bb = fid >> 5, k4 = (fid & 31) * 4;
            const float* src;
            if (isH) src = hin + (size_t)bb * D;
            else     src = toks ? (xbase + (size_t)tokl[bb] * D)
                                : (xbase + (size_t)bb * xbstride);
            *(float4*)&vec[bb][k4] = *(const float4*)(src + kc + k4);
        }
        __syncthreads();
        #pragma unroll
        for (int k4 = 0; k4 < 128; k4 += 4) {
            float4 wv = *(const float4*)(w + kc + k4);
            float4 xv = *(const float4*)&vec[b][k4];
            acc += wv.x * xv.x + wv.y * xv.y + wv.z * xv.z + wv.w * xv.w;
        }
    }
    gT[(size_t)rglob * 32 + b] = acc;
}

// ---------------------------------------------------------------------------
// K2: GRU combine -> h (fp32 + bf16); zero argz; pgen partials. grid 96 x 256.
// (Verbatim round-4.)
// ---------------------------------------------------------------------------
__global__ __launch_bounds__(256) void k_comb(
    const float* __restrict__ gT,
    const float* __restrict__ bih, const float* __restrict__ bhh,
    const float* __restrict__ hin,
    const float* __restrict__ xbase, long xbstride,
    const unsigned long long* __restrict__ toks,
    const float* __restrict__ wgen,
    float* __restrict__ hout, __bf16* __restrict__ hbf,
    float* __restrict__ pgen_part,
    unsigned long long* __restrict__ argz)
{
    __shared__ float part[8][32];
    const int t = threadIdx.x, bid = blockIdx.x;
    const int b = t & 31, dl = t >> 5;
    const int d = bid * 8 + dl;
    if (bid == 0 && t < 32) argz[t] = 0ULL;
    float ir = gT[(size_t)d * 32 + b]            + bih[d];
    float iz = gT[(size_t)(768 + d) * 32 + b]    + bih[768 + d];
    float in_ = gT[(size_t)(1536 + d) * 32 + b]  + bih[1536 + d];
    float hr = gT[(size_t)(2304 + d) * 32 + b]   + bhh[d];
    float hz = gT[(size_t)(3072 + d) * 32 + b]   + bhh[768 + d];
    float hn = gT[(size_t)(3840 + d) * 32 + b]   + bhh[1536 + d];
    float r = 1.0f / (1.0f + expf(-(ir + hr)));
    float z = 1.0f / (1.0f + expf(-(iz + hz)));
    float n = tanhf(in_ + r * hn);
    float hold = hin[(size_t)b * D + d];
    float hv = (1.0f - z) * n + z * hold;
    hout[(size_t)b * D + d] = hv;
    hbf[(size_t)b * D + d] = (__bf16)hv;
    float xv;
    if (toks) {
        int tok = (int)(0xFFFFFFFFu - (unsigned)(toks[b] & 0xFFFFFFFFull));
        xv = xbase[(size_t)tok * D + d];
    } else {
        xv = xbase[(size_t)b * xbstride + d];
    }
    part[dl][b] = wgen[d] * hv + wgen[768 + d] * xv;
    __syncthreads();
    if (t < 32) {
        float s = 0.f;
        #pragma unroll
        for (int i = 0; i < 8; ++i) s += part[i][t];
        pgen_part[(size_t)t * 96 + bid] = s;
    }
}

// ---------------------------------------------------------------------------
// K3: attn logit blocks FIRST (bid < NLG), then vocab MFMA blocks.
// (Verbatim round-4: global_load_lds staged, XOR-swizzled, counted vmcnt.)
// ---------------------------------------------------------------------------
struct __align__(16) MSE { float sh[64][33]; float dsum[32]; };
union  __align__(16) MSU { __bf16 buf[2][64][128]; MSE e; };

__device__ __forceinline__ void stage_chunk(
    const char* __restrict__ embb, int vb, int c, int w, int lane,
    char* lbuf, int V)
{
    #pragma unroll
    for (int i = 0; i < 4; ++i) {
        const int g = w * 4 + i;
        const int row = g * 4 + (lane >> 4);
        int grow = vb * 64 + row;
        grow = (grow < V) ? grow : (V - 1);
        const int cb = ((lane & 15) << 4) ^ ((row & 7) << 4);  // inverse swizzle on src
        const char* gp = embb + (size_t)grow * 1536 + (size_t)c * 256 + cb;
        char* lp = lbuf + g * 1024;                            // wave-uniform, linear dest
        __builtin_amdgcn_global_load_lds(
            (const __attribute__((address_space(1))) unsigned int*)gp,
            (__attribute__((address_space(3))) unsigned int*)lp, 16, 0, 0);
    }
}

__global__ __launch_bounds__(256) void k_mid(
    const float* __restrict__ hnew, const __bf16* __restrict__ hbf,
    const __bf16* __restrict__ embbf,
    const float* __restrict__ enc, const int* __restrict__ ids,
    float* __restrict__ out, long outoff, long JKV,
    float* __restrict__ dpartT, float* __restrict__ logitw,
    int V, int NVB)
{
    __shared__ MSU u;
    const int t = threadIdx.x;
    const int bid = blockIdx.x;

    if (bid < NLG) {
        // -------------------- attn logit block --------------------
        const int b = bid >> 2, c = bid & 3;
        const int x0 = c * 64;
        const int l = t & 31;
        float4 hr[6];
        #pragma unroll
        for (int p = 0; p < 6; ++p)
            hr[p] = *(const float4*)(hnew + (size_t)b * D + l * 4 + p * 128);
        #pragma unroll 4
        for (int g = 0; g < 8; ++g) {
            int x = x0 + g * 8 + (t >> 5);
            const float* er = enc + ((size_t)b * XX + x) * D + l * 4;
            float acc = 0.f;
            #pragma unroll
            for (int p = 0; p < 6; ++p) {
                float4 e = *(const float4*)(er + p * 128);
                acc += e.x * hr[p].x + e.y * hr[p].y + e.z * hr[p].z + e.w * hr[p].w;
            }
            #pragma unroll
            for (int m = 1; m <= 16; m <<= 1) acc += __shfl_xor(acc, m);
            if (l == 0) {
                int id = ids[b * XX + x];
                logitw[b * XX + x] = (id == 0) ? -1e9f : acc;
            }
        }
    } else {
        // -------------------- vocab MFMA block (LDS-staged) --------------------
        const int vb = bid - NLG;          // 0..NVB-1
        const int lane = t & 63, w = t >> 6;
        const int col = lane & 15;
        const int hi = lane >> 4;          // 0..3
        const int vrow = vb * 64 + w * 16 + col;
        const bool ok = vrow < V;
        const __bf16* ap0 = hbf + (size_t)col * D + hi * 8;
        const __bf16* ap1 = hbf + (size_t)(col + 16) * D + hi * 8;
        const char* embb = (const char*)embbf;

        // prologue: stage chunk 0
        stage_chunk(embb, vb, 0, w, lane, (char*)&u.buf[0][0][0], V);

        f32x4 c0 = {0.f, 0.f, 0.f, 0.f};
        f32x4 c1 = {0.f, 0.f, 0.f, 0.f};
        const int rl = w * 16 + col;
        const int swz = (rl & 7) << 4;
        for (int c = 0; c < 6; ++c) {
            if (c < 5) {
                stage_chunk(embb, vb, c + 1, w, lane,
                            (char*)&u.buf[(c + 1) & 1][0][0], V);
                asm volatile("s_waitcnt vmcnt(4)" ::: "memory");  // chunk c resident
            } else {
                asm volatile("s_waitcnt vmcnt(0)" ::: "memory");
            }
            const char* bbuf = (const char*)&u.buf[c & 1][0][0];
            #pragma unroll
            for (int q = 0; q < 4; ++q) {
                const int cbl = q * 64 + (hi << 4);
                bf16x8 bv = *(const bf16x8*)(bbuf + rl * 256 + (cbl ^ swz));
                const int kg = c * 128 + q * 32;
                bf16x8 a0 = *(const bf16x8*)(ap0 + kg);
                bf16x8 a1 = *(const bf16x8*)(ap1 + kg);
                c0 = __builtin_amdgcn_mfma_f32_16x16x32_bf16(a0, bv, c0, 0, 0, 0);
                c1 = __builtin_amdgcn_mfma_f32_16x16x32_bf16(a1, bv, c1, 0, 0, 0);
            }
        }

        // -------------------- epilogue (union reuse: sync first) --------------------
        __syncthreads();
        if (t < 32) u.e.dsum[t] = 0.f;
        __syncthreads();
        const int vloc = w * 16 + col;
        #pragma unroll
        for (int r = 0; r < 4; ++r) {
            int b0 = hi * 4 + r;
            float e0 = ok ? __expf(c0[r]) : 0.f;
            float e1 = ok ? __expf(c1[r]) : 0.f;
            u.e.sh[vloc][b0]      = e0;
            u.e.sh[vloc][b0 + 16] = e1;
            #pragma unroll
            for (int m = 1; m <= 8; m <<= 1) {
                e0 += __shfl_xor(e0, m);
                e1 += __shfl_xor(e1, m);
            }
            if (col == 0) {
                atomicAdd(&u.e.dsum[b0], e0);
                atomicAdd(&u.e.dsum[b0 + 16], e1);
            }
        }
        __syncthreads();
        if (t < 32) dpartT[(size_t)t * 512 + vb] = u.e.dsum[t];

        // coalesced store: each wave writes 8 b-rows, 64 consecutive floats
        const int vg = vb * 64 + lane;
        if (vg < V) {
            #pragma unroll
            for (int i = 0; i < 8; ++i) {
                int bb2 = w * 8 + i;
                out[(size_t)bb2 * JKV + outoff + vg] = u.e.sh[lane][bb2];
            }
        }
    }
}

// ---------------------------------------------------------------------------
// K4a: per-b prolog, ONCE (grid 32). Identical reduction trees to the R4 fin
// -> bit-identical rd, aw, pg. Writes aw_g[b][256], sc_g[b] = {pg, rd}.
// ---------------------------------------------------------------------------
__global__ __launch_bounds__(256) void k_pre(
    const float* __restrict__ dpartT, int npart,
    const float* __restrict__ logitw, const float* __restrict__ penc,
    const float* __restrict__ pgen_part, const float* __restrict__ bgen,
    float* __restrict__ aw_g, float* __restrict__ sc_g)
{
    __shared__ float red[256];
    const int t = threadIdx.x;
    const int b = blockIdx.x;

    // 1. denominator
    float s = 0.f;
    for (int i = t; i < npart; i += 256) s += dpartT[(size_t)b * 512 + i];
    red[t] = s;
    __syncthreads();
    for (int st = 128; st > 0; st >>= 1) {
        if (t < st) red[t] += red[t + st];
        __syncthreads();
    }
    const float rd = 1.0f / red[0];
    __syncthreads();

    // 2. attention softmax
    float l = logitw[b * XX + t];
    red[t] = l;
    __syncthreads();
    for (int st = 128; st > 0; st >>= 1) {
        if (t < st) red[t] = fmaxf(red[t], red[t + st]);
        __syncthreads();
    }
    float mx = red[0];
    __syncthreads();
    float e = expf(l - mx);
    red[t] = e;
    __syncthreads();
    for (int st = 128; st > 0; st >>= 1) {
        if (t < st) red[t] += red[t + st];
        __syncthreads();
    }
    float awv = e / red[0];
    aw_g[b * 256 + t] = awv;
    __syncthreads();

    // 3. p_gen
    float pv = awv * penc[b * XX + t] + ((t < 96) ? pgen_part[(size_t)b * 96 + t] : 0.f);
    red[t] = pv;
    __syncthreads();
    for (int st = 128; st > 0; st >>= 1) {
        if (t < st) red[t] += red[t + st];
        __syncthreads();
    }
    if (t == 0) {
        const float pg = 1.0f / (1.0f + expf(-(red[0] + bgen[0])));
        sc_g[b * 2]     = pg;
        sc_g[b * 2 + 1] = rd;
    }
}

// ---------------------------------------------------------------------------
// K4b: wide finalize. grid 1920 (32 b x 60 chunks of 512). No reduction
// trees, no redundancy: read 2 scalars + aw slice, LDS scatter, 2-iter RMW,
// block argmax -> atomicMax. Same expressions as R4 -> identical values.
// ---------------------------------------------------------------------------
__global__ __launch_bounds__(256) void k_finp(
    float* __restrict__ out, long outoff, long JKV,
    const float* __restrict__ aw_g, const float* __restrict__ sc_g,
    const int* __restrict__ ids,
    unsigned long long* __restrict__ argz, int V)
{
    __shared__ float pctx[CHS];
    __shared__ unsigned long long wmax[4];
    const int t = threadIdx.x;
    const int b = blockIdx.x / NCH;
    const int c = blockIdx.x % NCH;
    const int v0 = c * CHS;

    const float pg = sc_g[b * 2];
    const float rd = sc_g[b * 2 + 1];
    const float og = 1.0f - pg;

    pctx[t] = 0.f;
    pctx[256 + t] = 0.f;
    __syncthreads();
    {
        int id = ids[b * XX + t];
        float awv = aw_g[b * 256 + t];
        int rel = id - v0;
        if ((unsigned)rel < (unsigned)CHS) atomicAdd(&pctx[rel], awv);
    }
    __syncthreads();

    unsigned long long pk = 0ULL;
    const int vend = (v0 + CHS < V) ? CHS : (V - v0);
    #pragma unroll
    for (int i = 0; i < 2; ++i) {
        int v = t + 256 * i;
        if (v < vend) {
            int vg = v0 + v;
            size_t o = (size_t)b * JKV + outoff + vg;
            float ev = out[o];
            float ps = pg * ev * rd + og * pctx[v];
            out[o] = ps;
            unsigned long long k2 = ((unsigned long long)__float_as_uint(ps) << 32)
                                  | (unsigned long long)(0xFFFFFFFFu - (unsigned)vg);
            if (k2 > pk) pk = k2;
        }
    }
    #pragma unroll
    for (int m = 1; m < 64; m <<= 1) {
        unsigned long long o2 = __shfl_xor(pk, m);
        if (o2 > pk) pk = o2;
    }
    if ((t & 63) == 0) wmax[t >> 6] = pk;
    __syncthreads();
    if (t == 0) {
        unsigned long long m0 = wmax[0];
        #pragma unroll
        for (int i2 = 1; i2 < 4; ++i2) if (wmax[i2] > m0) m0 = wmax[i2];
        atomicMax(&argz[b], m0);
    }
}

// ---------------------------------------------------------------------------
extern "C" void kernel_launch(void* const* d_in, const int* in_sizes, int n_in,
                              void* d_out, int out_size, void* d_ws, size_t ws_size,
                              hipStream_t stream)
{
    const float* dec  = (const float*)d_in[0];
    const float* hid  = (const float*)d_in[1];
    const float* enc  = (const float*)d_in[2];
    const int*   ids  = (const int*)d_in[3];
    const float* emb  = (const float*)d_in[5];
    const float* wih  = (const float*)d_in[6];
    const float* whh  = (const float*)d_in[7];
    const float* bih  = (const float*)d_in[8];
    const float* bhh  = (const float*)d_in[9];
    const float* wgen = (const float*)d_in[10];
    const float* bgen = (const float*)d_in[11];
    float* out = (float*)d_out;

    const int B = 32;
    const int J = in_sizes[0] / (B * D);           // 4
    const int V = in_sizes[5] / D;                 // 30522
    const int K = out_size / (B * J * V);          // 8
    const long JKV = (long)J * K * V;
    const int NVB = (V + 63) / 64;                 // 477

    // workspace carve
    char* w = (char*)d_ws;
    unsigned long long* argpack = (unsigned long long*)w; w += 1024; // 2 x 32
    float* gT        = (float*)w;  w += (size_t)4608 * 32 * 4;
    float* dpartT    = (float*)w;  w += (size_t)32 * 512 * 4;
    float* logitw    = (float*)w;  w += (size_t)B * XX * 4;
    float* penc      = (float*)w;  w += (size_t)B * XX * 4;
    float* pgen_part = (float*)w;  w += (size_t)B * 96 * 4;
    float* h0        = (float*)w;  w += (size_t)B * D * 4;
    float* h1        = (float*)w;  w += (size_t)B * D * 4;
    float* aw_g      = (float*)w;  w += (size_t)B * 256 * 4;
    float* sc_g      = (float*)w;  w += (size_t)B * 2 * 4;
    __bf16* hbf      = (__bf16*)w; w += (size_t)B * D * 2;
    __bf16* embbf    = (__bf16*)w; w += (size_t)V * D * 2;

    const int n8 = V * D / 8;
    k_cvt<<<dim3((n8 + 255) / 256), dim3(256), 0, stream>>>(emb, embbf, n8);
    k_penc<<<dim3(128), dim3(256), 0, stream>>>(enc, wgen, penc);

    int step = 0;
    for (int j = 0; j < J; ++j) {
        for (int kk = 0; kk < K; ++kk) {
            const int cur = step & 1;
            float* hout = (cur == 0) ? h0 : h1;
            const float* hin = (step == 0) ? hid : ((((step - 1) & 1) == 0) ? h0 : h1);
            const float* xbase;
            long xbs;
            const unsigned long long* toks;
            if (kk == 0) {
                xbase = dec + (size_t)j * D;
                xbs = (long)J * D;
                toks = nullptr;
            } else {
                xbase = emb;
                xbs = D;
                toks = argpack + ((step - 1) & 1) * 32;
            }
            unsigned long long* argz = argpack + cur * 32;
            const long outoff = (long)(j * K + kk) * V;

            k_gates<<<dim3(576), dim3(256), 0, stream>>>(
                xbase, xbs, toks, hin, wih, whh, gT);
            k_comb<<<dim3(96), dim3(256), 0, stream>>>(
                gT, bih, bhh, hin, xbase, xbs, toks, wgen, hout, hbf,
                pgen_part, argz);
            k_mid<<<dim3(NVB + NLG), dim3(256), 0, stream>>>(
                hout, hbf, embbf, enc, ids, out, outoff, JKV,
                dpartT, logitw, V, NVB);
            k_pre<<<dim3(32), dim3(256), 0, stream>>>(
                dpartT, NVB, logitw, penc, pgen_part, bgen, aw_g, sc_g);
            k_finp<<<dim3(32 * NCH), dim3(256), 0, stream>>>(
                out, outoff, JKV, aw_g, sc_g, ids, argz, V);
            ++step;
        }
    }
}

// Round 10
// 2277.230 us; speedup vs baseline: 1.6823x; 1.1203x over previous
//
#include <hip/hip_runtime.h>
#include <hip/hip_bf16.h>

#define D 768
#define BB 32
#define XX 256
#define CH 3816   // vocab chunk per k_fin block (8 chunks cover 30522)
#define NLG 128   // attn logit blocks (scheduled first in k_mid)

typedef __bf16 bf16x8 __attribute__((ext_vector_type(8)));
typedef float  f32x4  __attribute__((ext_vector_type(4)));

// ---------------------------------------------------------------------------
// K0: one-time: emb fp32 -> bf16, TILED layout:
// embt[vb][c][row][256B]  (vb = 64-row tile, c = 128-elem k-chunk, row 0..63)
// -> each k_mid stage instruction reads 1KB CONTIGUOUS; a block's tile is one
// sequential 96KB sweep (DRAM page opened once, not 6x). Rows >= V: zeros
// (consumed only by discarded lanes).
// ---------------------------------------------------------------------------
__global__ __launch_bounds__(256) void k_cvt(const float* __restrict__ src,
                                             __bf16* __restrict__ dst,
                                             int n16, int V)
{
    int i = blockIdx.x * 256 + threadIdx.x;
    if (i >= n16) return;
    const int vb  = i / 6144;            // 6*64*16 units per tile
    const int rem = i - vb * 6144;
    const int c   = rem >> 10;           // 0..5
    const int r2  = rem & 1023;
    const int row = r2 >> 4;             // 0..63
    const int u   = r2 & 15;             // 16B unit within 256B chunk
    const int grow = vb * 64 + row;
    bf16x8 o = {};
    if (grow < V) {
        const float* s = src + (size_t)grow * D + c * 128 + u * 8;
        float4 f0 = *(const float4*)(s);
        float4 f1 = *(const float4*)(s + 4);
        o[0] = (__bf16)f0.x; o[1] = (__bf16)f0.y; o[2] = (__bf16)f0.z; o[3] = (__bf16)f0.w;
        o[4] = (__bf16)f1.x; o[5] = (__bf16)f1.y; o[6] = (__bf16)f1.z; o[7] = (__bf16)f1.w;
    }
    *(bf16x8*)(dst + (size_t)i * 8) = o;
}

// ---------------------------------------------------------------------------
// K0b: one-time: penc[b][x] = wgen[1536:2304] . enc[b,x,:]
// ---------------------------------------------------------------------------
__global__ __launch_bounds__(256) void k_penc(
    const float* __restrict__ enc, const float* __restrict__ wgen,
    float* __restrict__ penc)
{
    const int t = threadIdx.x;
    const int b = blockIdx.x >> 2, c = blockIdx.x & 3;
    const int x0 = c * 64;
    const int l = t & 31;
    float4 wr[6];
    #pragma unroll
    for (int p = 0; p < 6; ++p)
        wr[p] = *(const float4*)(wgen + 1536 + l * 4 + p * 128);
    for (int g = 0; g < 8; ++g) {
        int x = x0 + g * 8 + (t >> 5);
        const float* er = enc + ((size_t)b * XX + x) * D + l * 4;
        float acc = 0.f;
        #pragma unroll
        for (int p = 0; p < 6; ++p) {
            float4 e = *(const float4*)(er + p * 128);
            acc += e.x * wr[p].x + e.y * wr[p].y + e.z * wr[p].z + e.w * wr[p].w;
        }
        #pragma unroll
        for (int m = 1; m <= 16; m <<= 1) acc += __shfl_xor(acc, m);
        if (l == 0) penc[b * XX + x] = acc;
    }
}

// ---------------------------------------------------------------------------
// K1: GRU gates GEMM, fp32. gT[row 0..4607][b 0..31]. grid 576 x 256.
// (Verbatim round-4 best.)
// ---------------------------------------------------------------------------
__global__ __launch_bounds__(256) void k_gates(
    const float* __restrict__ xbase, long xbstride,
    const unsigned long long* __restrict__ toks,
    const float* __restrict__ hin,
    const float* __restrict__ wih, const float* __restrict__ whh,
    float* __restrict__ gT)
{
    __shared__ __align__(16) float vec[BB][132];
    __shared__ int tokl[BB];
    const int t = threadIdx.x, bid = blockIdx.x;
    const int b = t & 31, rl = t >> 5;
    const int rglob = bid * 8 + rl;
    const bool isH = rglob >= 2304;
    const int row = isH ? rglob - 2304 : rglob;
    const float* w = (isH ? whh : wih) + (size_t)row * D;
    if (t < 32) tokl[t] = toks ? (int)(0xFFFFFFFFu - (unsigned)(toks[t] & 0xFFFFFFFFull)) : 0;

    float acc = 0.f;
    for (int c = 0; c < 6; ++c) {
        const int kc = c * 128;
        __syncthreads();
        for (int p = 0; p < 4; ++p) {
            int fid = t + 256 * p;
            int bb = fid >> 5, k4 = (fid & 31) * 4;
            const float* src;
            if (isH) src = hin + (size_t)bb * D;
            else     src = toks ? (xbase + (size_t)tokl[bb] * D)
                                : (xbase + (size_t)bb * xbstride);
            *(float4*)&vec[bb][k4] = *(const float4*)(src + kc + k4);
        }
        __syncthreads();
        #pragma unroll
        for (int k4 = 0; k4 < 128; k4 += 4) {
            float4 wv = *(const float4*)(w + kc + k4);
            float4 xv = *(const float4*)&vec[b][k4];
            acc += wv.x * xv.x + wv.y * xv.y + wv.z * xv.z + wv.w * xv.w;
        }
    }
    gT[(size_t)rglob * 32 + b] = acc;
}

// ---------------------------------------------------------------------------
// K2: GRU combine -> h (fp32 + bf16); zero argz; pgen partials. grid 96 x 256.
// (Verbatim round-4.)
// ---------------------------------------------------------------------------
__global__ __launch_bounds__(256) void k_comb(
    const float* __restrict__ gT,
    const float* __restrict__ bih, const float* __restrict__ bhh,
    const float* __restrict__ hin,
    const float* __restrict__ xbase, long xbstride,
    const unsigned long long* __restrict__ toks,
    const float* __restrict__ wgen,
    float* __restrict__ hout, __bf16* __restrict__ hbf,
    float* __restrict__ pgen_part,
    unsigned long long* __restrict__ argz)
{
    __shared__ float part[8][32];
    const int t = threadIdx.x, bid = blockIdx.x;
    const int b = t & 31, dl = t >> 5;
    const int d = bid * 8 + dl;
    if (bid == 0 && t < 32) argz[t] = 0ULL;
    float ir = gT[(size_t)d * 32 + b]            + bih[d];
    float iz = gT[(size_t)(768 + d) * 32 + b]    + bih[768 + d];
    float in_ = gT[(size_t)(1536 + d) * 32 + b]  + bih[1536 + d];
    float hr = gT[(size_t)(2304 + d) * 32 + b]   + bhh[d];
    float hz = gT[(size_t)(3072 + d) * 32 + b]   + bhh[768 + d];
    float hn = gT[(size_t)(3840 + d) * 32 + b]   + bhh[1536 + d];
    float r = 1.0f / (1.0f + expf(-(ir + hr)));
    float z = 1.0f / (1.0f + expf(-(iz + hz)));
    float n = tanhf(in_ + r * hn);
    float hold = hin[(size_t)b * D + d];
    float hv = (1.0f - z) * n + z * hold;
    hout[(size_t)b * D + d] = hv;
    hbf[(size_t)b * D + d] = (__bf16)hv;
    float xv;
    if (toks) {
        int tok = (int)(0xFFFFFFFFu - (unsigned)(toks[b] & 0xFFFFFFFFull));
        xv = xbase[(size_t)tok * D + d];
    } else {
        xv = xbase[(size_t)b * xbstride + d];
    }
    part[dl][b] = wgen[d] * hv + wgen[768 + d] * xv;
    __syncthreads();
    if (t < 32) {
        float s = 0.f;
        #pragma unroll
        for (int i = 0; i < 8; ++i) s += part[i][t];
        pgen_part[(size_t)t * 96 + bid] = s;
    }
}

// ---------------------------------------------------------------------------
// K3: attn logit blocks FIRST (bid < NLG), then vocab MFMA blocks.
// Vocab path: TILED embbf (sequential 1KB reads per instruction); pipeline,
// swizzle, LDS image and MFMA path identical to round-4.
// ---------------------------------------------------------------------------
struct __align__(16) MSE { float sh[64][33]; float dsum[32]; };
union  __align__(16) MSU { __bf16 buf[2][64][128]; MSE e; };

__device__ __forceinline__ void stage_chunk(
    const char* __restrict__ embt, int vb, int c, int w, int lane,
    char* lbuf)
{
    const char* base = embt + ((size_t)(vb * 6 + c) << 14);  // 16KB per (vb,c)
    #pragma unroll
    for (int i = 0; i < 4; ++i) {
        const int g = w * 4 + i;
        const int row = g * 4 + (lane >> 4);
        const int cb = ((lane & 15) << 4) ^ ((row & 7) << 4); // intra-128B swizzle
        const char* gp = base + (size_t)row * 256 + cb;       // sequential lines
        char* lp = lbuf + g * 1024;                           // wave-uniform, linear dest
        __builtin_amdgcn_global_load_lds(
            (const __attribute__((address_space(1))) unsigned int*)gp,
            (__attribute__((address_space(3))) unsigned int*)lp, 16, 0, 0);
    }
}

__global__ __launch_bounds__(256) void k_mid(
    const float* __restrict__ hnew, const __bf16* __restrict__ hbf,
    const __bf16* __restrict__ embt,
    const float* __restrict__ enc, const int* __restrict__ ids,
    float* __restrict__ out, long outoff, long JKV,
    float* __restrict__ dpartT, float* __restrict__ logitw,
    int V, int NVB)
{
    __shared__ MSU u;
    const int t = threadIdx.x;
    const int bid = blockIdx.x;

    if (bid < NLG) {
        // -------------------- attn logit block --------------------
        const int b = bid >> 2, c = bid & 3;
        const int x0 = c * 64;
        const int l = t & 31;
        float4 hr[6];
        #pragma unroll
        for (int p = 0; p < 6; ++p)
            hr[p] = *(const float4*)(hnew + (size_t)b * D + l * 4 + p * 128);
        #pragma unroll 4
        for (int g = 0; g < 8; ++g) {
            int x = x0 + g * 8 + (t >> 5);
            const float* er = enc + ((size_t)b * XX + x) * D + l * 4;
            float acc = 0.f;
            #pragma unroll
            for (int p = 0; p < 6; ++p) {
                float4 e = *(const float4*)(er + p * 128);
                acc += e.x * hr[p].x + e.y * hr[p].y + e.z * hr[p].z + e.w * hr[p].w;
            }
            #pragma unroll
            for (int m = 1; m <= 16; m <<= 1) acc += __shfl_xor(acc, m);
            if (l == 0) {
                int id = ids[b * XX + x];
                logitw[b * XX + x] = (id == 0) ? -1e9f : acc;
            }
        }
    } else {
        // -------------------- vocab MFMA block (LDS-staged) --------------------
        const int vb = bid - NLG;          // 0..NVB-1
        const int lane = t & 63, w = t >> 6;
        const int col = lane & 15;
        const int hi = lane >> 4;          // 0..3
        const int vrow = vb * 64 + w * 16 + col;
        const bool ok = vrow < V;
        const __bf16* ap0 = hbf + (size_t)col * D + hi * 8;
        const __bf16* ap1 = hbf + (size_t)(col + 16) * D + hi * 8;
        const char* embb = (const char*)embt;

        // prologue: stage chunk 0
        stage_chunk(embb, vb, 0, w, lane, (char*)&u.buf[0][0][0]);

        f32x4 c0 = {0.f, 0.f, 0.f, 0.f};
        f32x4 c1 = {0.f, 0.f, 0.f, 0.f};
        const int rl = w * 16 + col;
        const int swz = (rl & 7) << 4;
        for (int c = 0; c < 6; ++c) {
            if (c < 5) {
                stage_chunk(embb, vb, c + 1, w, lane,
                            (char*)&u.buf[(c + 1) & 1][0][0]);
                asm volatile("s_waitcnt vmcnt(4)" ::: "memory");  // chunk c resident
            } else {
                asm volatile("s_waitcnt vmcnt(0)" ::: "memory");
            }
            const char* bbuf = (const char*)&u.buf[c & 1][0][0];
            #pragma unroll
            for (int q = 0; q < 4; ++q) {
                const int cbl = q * 64 + (hi << 4);
                bf16x8 bv = *(const bf16x8*)(bbuf + rl * 256 + (cbl ^ swz));
                const int kg = c * 128 + q * 32;
                bf16x8 a0 = *(const bf16x8*)(ap0 + kg);
                bf16x8 a1 = *(const bf16x8*)(ap1 + kg);
                c0 = __builtin_amdgcn_mfma_f32_16x16x32_bf16(a0, bv, c0, 0, 0, 0);
                c1 = __builtin_amdgcn_mfma_f32_16x16x32_bf16(a1, bv, c1, 0, 0, 0);
            }
        }

        // -------------------- epilogue (union reuse: sync first) --------------------
        __syncthreads();
        if (t < 32) u.e.dsum[t] = 0.f;
        __syncthreads();
        const int vloc = w * 16 + col;
        #pragma unroll
        for (int r = 0; r < 4; ++r) {
            int b0 = hi * 4 + r;
            float e0 = ok ? __expf(c0[r]) : 0.f;
            float e1 = ok ? __expf(c1[r]) : 0.f;
            u.e.sh[vloc][b0]      = e0;
            u.e.sh[vloc][b0 + 16] = e1;
            #pragma unroll
            for (int m = 1; m <= 8; m <<= 1) {
                e0 += __shfl_xor(e0, m);
                e1 += __shfl_xor(e1, m);
            }
            if (col == 0) {
                atomicAdd(&u.e.dsum[b0], e0);
                atomicAdd(&u.e.dsum[b0 + 16], e1);
            }
        }
        __syncthreads();
        if (t < 32) dpartT[(size_t)t * 512 + vb] = u.e.dsum[t];

        // coalesced store: each wave writes 8 b-rows, 64 consecutive floats
        const int vg = vb * 64 + lane;
        if (vg < V) {
            #pragma unroll
            for (int i = 0; i < 8; ++i) {
                int bb2 = w * 8 + i;
                out[(size_t)bb2 * JKV + outoff + vg] = u.e.sh[lane][bb2];
            }
        }
    }
}

// ---------------------------------------------------------------------------
// K4: finalize (verbatim round-4 best: grid 256, CH=3816).
// ---------------------------------------------------------------------------
__global__ __launch_bounds__(256) void k_fin(
    float* __restrict__ out, long outoff, long JKV,
    const float* __restrict__ dpartT, int npart,
    const float* __restrict__ logitw, const float* __restrict__ penc,
    const float* __restrict__ pgen_part, const float* __restrict__ bgen,
    const int* __restrict__ ids,
    unsigned long long* __restrict__ argz, int V)
{
    __shared__ float pctx[CH];
    __shared__ float red[256];
    __shared__ float aw[256];
    __shared__ unsigned long long wmax[4];
    const int t = threadIdx.x;
    const int b = blockIdx.x >> 3;
    const int c = blockIdx.x & 7;
    const int v0 = c * CH;

    // 1. denominator
    float s = 0.f;
    for (int i = t; i < npart; i += 256) s += dpartT[(size_t)b * 512 + i];
    red[t] = s;
    __syncthreads();
    for (int st = 128; st > 0; st >>= 1) {
        if (t < st) red[t] += red[t + st];
        __syncthreads();
    }
    const float rd = 1.0f / red[0];
    __syncthreads();

    // 2. attention softmax
    float l = logitw[b * XX + t];
    red[t] = l;
    __syncthreads();
    for (int st = 128; st > 0; st >>= 1) {
        if (t < st) red[t] = fmaxf(red[t], red[t + st]);
        __syncthreads();
    }
    float mx = red[0];
    __syncthreads();
    float e = expf(l - mx);
    red[t] = e;
    __syncthreads();
    for (int st = 128; st > 0; st >>= 1) {
        if (t < st) red[t] += red[t + st];
        __syncthreads();
    }
    float awv = e / red[0];
    aw[t] = awv;
    __syncthreads();

    // 3. p_gen
    float pv = awv * penc[b * XX + t] + ((t < 96) ? pgen_part[(size_t)b * 96 + t] : 0.f);
    red[t] = pv;
    __syncthreads();
    for (int st = 128; st > 0; st >>= 1) {
        if (t < st) red[t] += red[t + st];
        __syncthreads();
    }
    const float pg = 1.0f / (1.0f + expf(-(red[0] + bgen[0])));
    const float og = 1.0f - pg;

    // 4. scatter p_ctx chunk
    for (int i = t; i < CH; i += 256) pctx[i] = 0.f;
    __syncthreads();
    {
        int id = ids[b * XX + t];
        int rel = id - v0;
        if ((unsigned)rel < (unsigned)CH) atomicAdd(&pctx[rel], aw[t]);
    }
    __syncthreads();

    // 5. normalize + argmax
    unsigned long long pk = 0ULL;
    const int vend = (v0 + CH < V) ? CH : (V - v0);
    #pragma unroll
    for (int i = 0; i < 15; ++i) {
        int v = t + 256 * i;
        if (v < vend) {
            int vg = v0 + v;
            size_t o = (size_t)b * JKV + outoff + vg;
            float ev = out[o];
            float ps = pg * ev * rd + og * pctx[v];
            out[o] = ps;
            unsigned long long k2 = ((unsigned long long)__float_as_uint(ps) << 32)
                                  | (unsigned long long)(0xFFFFFFFFu - (unsigned)vg);
            if (k2 > pk) pk = k2;
        }
    }
    #pragma unroll
    for (int m = 1; m < 64; m <<= 1) {
        unsigned long long o2 = __shfl_xor(pk, m);
        if (o2 > pk) pk = o2;
    }
    if ((t & 63) == 0) wmax[t >> 6] = pk;
    __syncthreads();
    if (t == 0) {
        unsigned long long m0 = wmax[0];
        #pragma unroll
        for (int i2 = 1; i2 < 4; ++i2) if (wmax[i2] > m0) m0 = wmax[i2];
        atomicMax(&argz[b], m0);
    }
}

// ---------------------------------------------------------------------------
extern "C" void kernel_launch(void* const* d_in, const int* in_sizes, int n_in,
                              void* d_out, int out_size, void* d_ws, size_t ws_size,
                              hipStream_t stream)
{
    const float* dec  = (const float*)d_in[0];
    const float* hid  = (const float*)d_in[1];
    const float* enc  = (const float*)d_in[2];
    const int*   ids  = (const int*)d_in[3];
    const float* emb  = (const float*)d_in[5];
    const float* wih  = (const float*)d_in[6];
    const float* whh  = (const float*)d_in[7];
    const float* bih  = (const float*)d_in[8];
    const float* bhh  = (const float*)d_in[9];
    const float* wgen = (const float*)d_in[10];
    const float* bgen = (const float*)d_in[11];
    float* out = (float*)d_out;

    const int B = 32;
    const int J = in_sizes[0] / (B * D);           // 4
    const int V = in_sizes[5] / D;                 // 30522
    const int K = out_size / (B * J * V);          // 8
    const long JKV = (long)J * K * V;
    const int NVB = (V + 63) / 64;                 // 477

    // workspace carve
    char* w = (char*)d_ws;
    unsigned long long* argpack = (unsigned long long*)w; w += 1024; // 2 x 32
    float* gT        = (float*)w;  w += (size_t)4608 * 32 * 4;
    float* dpartT    = (float*)w;  w += (size_t)32 * 512 * 4;
    float* logitw    = (float*)w;  w += (size_t)B * XX * 4;
    float* penc      = (float*)w;  w += (size_t)B * XX * 4;
    float* pgen_part = (float*)w;  w += (size_t)B * 96 * 4;
    float* h0        = (float*)w;  w += (size_t)B * D * 4;
    float* h1        = (float*)w;  w += (size_t)B * D * 4;
    __bf16* hbf      = (__bf16*)w; w += (size_t)B * D * 2;
    __bf16* embt     = (__bf16*)w; w += (size_t)NVB * 98304;  // tiled: 96KB/tile

    const int n16 = NVB * 6144;                    // 16B units in tiled embbf
    k_cvt<<<dim3((n16 + 255) / 256), dim3(256), 0, stream>>>(emb, embt, n16, V);
    k_penc<<<dim3(128), dim3(256), 0, stream>>>(enc, wgen, penc);

    int step = 0;
    for (int j = 0; j < J; ++j) {
        for (int kk = 0; kk < K; ++kk) {
            const int cur = step & 1;
            float* hout = (cur == 0) ? h0 : h1;
            const float* hin = (step == 0) ? hid : ((((step - 1) & 1) == 0) ? h0 : h1);
            const float* xbase;
            long xbs;
            const unsigned long long* toks;
            if (kk == 0) {
                xbase = dec + (size_t)j * D;
                xbs = (long)J * D;
                toks = nullptr;
            } else {
                xbase = emb;
                xbs = D;
                toks = argpack + ((step - 1) & 1) * 32;
            }
            unsigned long long* argz = argpack + cur * 32;
            const long outoff = (long)(j * K + kk) * V;

            k_gates<<<dim3(576), dim3(256), 0, stream>>>(
                xbase, xbs, toks, hin, wih, whh, gT);
            k_comb<<<dim3(96), dim3(256), 0, stream>>>(
                gT, bih, bhh, hin, xbase, xbs, toks, wgen, hout, hbf,
                pgen_part, argz);
            k_mid<<<dim3(NVB + NLG), dim3(256), 0, stream>>>(
                hout, hbf, embt, enc, ids, out, outoff, JKV,
                dpartT, logitw, V, NVB);
            k_fin<<<dim3(256), dim3(256), 0, stream>>>(
                out, outoff, JKV, dpartT, NVB, logitw, penc, pgen_part,
                bgen, ids, argz, V);
            ++step;
        }
    }
}